// Round 3
// baseline (42979.996 us; speedup 1.0000x reference)
//
#include <hip/hip_runtime.h>
#include <stdint.h>

#define NBLK 256
#define NTHR 512

typedef __attribute__((ext_vector_type(8))) short short8;
typedef __attribute__((ext_vector_type(4))) float float4_;

// ---- workspace ----
// BAR: per-Rg sets at lines 32+Rg*16+(0..9) (leaf 0..7, root 8, gen 9). memset first 12288 B.
#define WS_BAR  0
#define WS_HDNF 16384                     // hdn fragments: 4Rg * 32 * 512 shorts = 131072 B
#define WS_KF   (16384 + 131072)          // 2 x 512*64 f32 (double-buffered k) = 262144 B

#define LOADC(p)    __hip_atomic_load((p),  __ATOMIC_RELAXED, __HIP_MEMORY_SCOPE_SYSTEM)
#define STOREC(p,v) __hip_atomic_store((p), (v), __ATOMIC_RELAXED, __HIP_MEMORY_SCOPE_SYSTEM)

__device__ __forceinline__ unsigned short f2bf(float x) {
  union { float f; unsigned u; } v; v.f = x;
  return (unsigned short)((v.u + 0x7fffu + ((v.u >> 16) & 1u)) >> 16);
}
__device__ __forceinline__ float fast_exp(float x) {
  return __builtin_amdgcn_exp2f(x * 1.4426950408889634f);
}
__device__ __forceinline__ float fast_tanh(float x) {
  float e = __builtin_amdgcn_exp2f(x * 2.8853900817779268f);
  return fmaf(-2.0f, __builtin_amdgcn_rcpf(e + 1.0f), 1.0f);
}
__device__ __forceinline__ float fast_silu(float x) {
  float e = fast_exp(-x);
  return x * __builtin_amdgcn_rcpf(1.0f + e);
}

// Row-group-local barrier over 64 blocks: 8 leaves x 8 (leaf = h&7) + root + gen.
// Proven design: one arriving lane per block, fetch_add tree, gen poll + s_sleep.
__device__ __forceinline__ void rgbar(unsigned* bar, int h, int Rg, unsigned bn) {
  __syncthreads();
  if (threadIdx.x == 0) {
    unsigned* base = bar + 32 * (32 + Rg * 16);
    unsigned* leaf = base + 32 * (h & 7);
    unsigned* root = base + 32 * 8;
    unsigned* gen  = base + 32 * 9;
    unsigned a = __hip_atomic_fetch_add(leaf, 1u, __ATOMIC_RELAXED, __HIP_MEMORY_SCOPE_SYSTEM);
    if (a == 8u * bn - 1u) {
      unsigned r = __hip_atomic_fetch_add(root, 1u, __ATOMIC_RELAXED, __HIP_MEMORY_SCOPE_SYSTEM);
      if (r == 8u * bn - 1u) STOREC(gen, bn);
    }
    while (LOADC(gen) < bn) __builtin_amdgcn_s_sleep(1);
  }
  __syncthreads();
}

template<int SIN>
__device__ __forceinline__ void rk_stage(
    int stepi, int sg, int h, int Rg, int R, int r0,
    float (&kh)[6], float& y, float t0v, float dtv,
    const float4_ (&wr1)[16], const float4_ (&wr2)[16],
    float b0r, float b1r, float b2r,
    unsigned char* ws, unsigned* BAR, unsigned& rseq,
    const float* logsig, const float* w0,
    unsigned short* w3lds, float* b3lds, float* intv,
    float (*yst)[64], float (*hb1)[128], float (*hb2)[128],
    unsigned short (*hdnS)[128], int* sidxp) {
  const int tid = threadIdx.x;
  const int lane = tid & 63, wv = tid >> 6;
  const int col = lane & 15, qd = lane >> 4;
  // MLP mapping: tid = (row<<8) | (jhi<<6) | (half<<5) | jlo ; j = jhi*32+jlo
  const int mrow = tid >> 8, mj = ((tid >> 6) & 3) * 32 + (tid & 31), mhalf = (tid >> 5) & 1;
  unsigned* HDNF = (unsigned*)(ws + WS_HDNF);
  float* KF  = (float*)(ws + WS_KF);

  // ---- phase 1: ingest k (2 rows), RK combine, MLP ----
  if (sg > 0 && tid < 128) {
    const float* KFr = KF + ((sg & 1) ^ 1) * 32768;
    constexpr int pi = (SIN == 0) ? 5 : SIN - 1;
    kh[pi] = LOADC(&KFr[(size_t)(r0 + (tid >> 6)) * 64 + (tid & 63)]);
  }
  if (tid < 128) {
    float ystv;
    if constexpr (SIN == 0) {
      if (sg > 0) {
        y += dtv * (0.09646076681806523f * kh[0] + 0.01f * kh[1]
                  + 0.4798896504144996f * kh[2] + 1.379008574103742f * kh[3]
                  - 3.290069515436081f * kh[4] + 2.324710524099774f * kh[5]);
      }
      ystv = y;
    } else if constexpr (SIN == 1) {
      ystv = y + dtv * (0.161f * kh[0]);
    } else if constexpr (SIN == 2) {
      ystv = y + dtv * (-0.008480655492356989f * kh[0] + 0.335480655492357f * kh[1]);
    } else if constexpr (SIN == 3) {
      ystv = y + dtv * (2.8971530571054935f * kh[0] - 6.359448489975075f * kh[1]
                      + 4.3622954328695815f * kh[2]);
    } else if constexpr (SIN == 4) {
      ystv = y + dtv * (5.325864828439257f * kh[0] - 11.748883564062828f * kh[1]
                      + 7.4955393428898365f * kh[2] - 0.09249506636175525f * kh[3]);
    } else {
      ystv = y + dtv * (5.86145544294642f * kh[0] - 12.92096931784711f * kh[1]
                      + 8.159367898576159f * kh[2] - 0.071584973281401f * kh[3]
                      - 0.028269050394068383f * kh[4]);
    }
    yst[tid >> 6][tid & 63] = ystv;
  }
  // searchsorted for current stage time (exact f32 compare vs intervals input)
  {
    float tb = __fadd_rn(t0v, __fmul_rn((float)stepi, dtv));
    float t_cur;
    if constexpr (SIN == 0) t_cur = tb;
    else {
      constexpr float cS = (SIN == 1) ? 0.161f : (SIN == 2) ? 0.327f : (SIN == 3) ? 0.9f
                         : (SIN == 4) ? 0.9800255409045097f : 1.0f;
      t_cur = __fadd_rn(tb, __fmul_rn(cS, dtv));
    }
    if (tid < 64) {
      unsigned long long m1 = __ballot(intv[tid] < t_cur);
      if (tid == 0) *sidxp = (int)__popcll(m1);
    }
  }
  __syncthreads();
  const int idx = *sidxp;

  // MLP layer 1 (w0 streamed, K=64 half-split): all 512 threads
  {
    const float4_* wrp = (const float4_*)(w0 + (size_t)mj * 64 + mhalf * 32);
    const float* yp = &yst[mrow][mhalf * 32];
    float ac0 = 0.0f, ac1 = 0.0f;
    #pragma unroll
    for (int i4 = 0; i4 < 8; ++i4) {
      float4_ wvv = wrp[i4];
      float s = fmaf(yp[4*i4+0], wvv[0], yp[4*i4+1] * wvv[1]);
      s = fmaf(yp[4*i4+2], wvv[2], s);
      s = fmaf(yp[4*i4+3], wvv[3], s);
      if (i4 & 1) ac1 += s; else ac0 += s;
    }
    float v = ac0 + ac1;
    v += __shfl_xor(v, 32);
    if (mhalf == 0) hb1[mrow][mj] = fast_silu(v + b0r);
  }
  __syncthreads();
  // MLP layer 2 (w1 in VGPRs)
  {
    const float* hp = &hb1[mrow][mhalf * 64];
    float ac0 = 0.0f, ac1 = 0.0f;
    #pragma unroll
    for (int i4 = 0; i4 < 16; ++i4) {
      float4_ wvv = wr1[i4];
      float s = fmaf(hp[4*i4+0], wvv[0], hp[4*i4+1] * wvv[1]);
      s = fmaf(hp[4*i4+2], wvv[2], s);
      s = fmaf(hp[4*i4+3], wvv[3], s);
      if (i4 & 1) ac1 += s; else ac0 += s;
    }
    float v = ac0 + ac1;
    v += __shfl_xor(v, 32);
    if (mhalf == 0) hb2[mrow][mj] = fast_silu(v + b1r);
  }
  __syncthreads();
  // MLP layer 3 (w2 in VGPRs) -> bf16 hdn
  {
    const float* hp = &hb2[mrow][mhalf * 64];
    float ac0 = 0.0f, ac1 = 0.0f;
    #pragma unroll
    for (int i4 = 0; i4 < 16; ++i4) {
      float4_ wvv = wr2[i4];
      float s = fmaf(hp[4*i4+0], wvv[0], hp[4*i4+1] * wvv[1]);
      s = fmaf(hp[4*i4+2], wvv[2], s);
      s = fmaf(hp[4*i4+3], wvv[3], s);
      if (i4 & 1) ac1 += s; else ac0 += s;
    }
    float v = ac0 + ac1;
    v += __shfl_xor(v, 32);
    if (mhalf == 0) hdnS[mrow][mj] = f2bf(fast_silu(v + b2r));
  }
  __syncthreads();
  // pack-store hdn into A-fragment layout in WS (dword stores)
  if (tid < 128) {
    const int row = tid >> 6, u = tid & 63;
    const int lb = 2 * h + row;            // local row within Rg
    const int tile = lb >> 4, colp = lb & 15;
    const int j0 = 2 * u;
    const int kb = j0 >> 5, qdp = (j0 >> 3) & 3, jj = j0 & 7;
    unsigned v = (unsigned)hdnS[row][j0] | ((unsigned)hdnS[row][j0 + 1] << 16);
    unsigned i16 = (unsigned)((Rg * 32 + tile * 4 + kb) * 512 + qdp * 128 + colp * 8 + jj);
    STOREC(&HDNF[i16 >> 1], v);
  }
  // ---- barrier 1: hdn exchange within row-group ----
  ++rseq; rgbar(BAR, h, Rg, rseq);

  // ---- phase 2: GEMM 128 x 528 x 128 (wave wv owns m-tile wv), no internal syncs ----
  {
    const unsigned long long* H64 = (const unsigned long long*)HDNF;
    union { unsigned long long u[2]; short8 s; } af[4];
    #pragma unroll
    for (int kb = 0; kb < 4; ++kb) {
      const unsigned i16 = (unsigned)((Rg * 32 + wv * 4 + kb) * 512 + lane * 8);
      af[kb].u[0] = LOADC(&H64[i16 >> 2]);
      af[kb].u[1] = LOADC(&H64[(i16 >> 2) + 1]);
    }
    // direct reads of read-only logsig[b][idx][1+l] (L2-resident per XCD pair)
    const float* sp0 = logsig + (size_t)(R + wv * 16 + qd * 4) * 34385 + (size_t)idx * 529 + 1;
    const float* sp1 = sp0 + 34385;
    const float* sp2 = sp0 + 2 * 34385;
    const float* sp3 = sp0 + 3 * 34385;
    float kp[4] = {0.0f, 0.0f, 0.0f, 0.0f};
    #pragma unroll 2
    for (int nt = 0; nt < 33; ++nt) {
      const int l = nt * 16 + col;
      const float bv = b3lds[l];
      float4_ acc; acc[0] = bv; acc[1] = bv; acc[2] = bv; acc[3] = bv;
      #pragma unroll
      for (int kb = 0; kb < 4; ++kb) {
        const short8 bf = *(const short8*)(w3lds + ((nt * 4 + kb) * 64 + lane) * 8);
        acc = __builtin_amdgcn_mfma_f32_16x16x32_bf16(af[kb].s, bf, acc, 0, 0, 0);
      }
      kp[0] = fmaf(fast_tanh(acc[0]), sp0[l], kp[0]);
      kp[1] = fmaf(fast_tanh(acc[1]), sp1[l], kp[1]);
      kp[2] = fmaf(fast_tanh(acc[2]), sp2[l], kp[2]);
      kp[3] = fmaf(fast_tanh(acc[3]), sp3[l], kp[3]);
    }
    #pragma unroll
    for (int r = 0; r < 4; ++r) {
      float v = kp[r];
      v += __shfl_xor(v, 1); v += __shfl_xor(v, 2);
      v += __shfl_xor(v, 4); v += __shfl_xor(v, 8);
      kp[r] = v;
    }
    if (col == 0) {
      float* KFw = KF + (sg & 1) * 32768;
      #pragma unroll
      for (int r = 0; r < 4; ++r)
        STOREC(&KFw[(size_t)(R + wv * 16 + qd * 4 + r) * 64 + h], kp[r]);
    }
  }
  // ---- barrier 2: k exchange within row-group ----
  ++rseq; rgbar(BAR, h, Rg, rseq);
}

__global__ void __launch_bounds__(NTHR, 2)
rde_kernel(const float* __restrict__ ts, const float* __restrict__ logsig,
           const float* __restrict__ x0, const float* __restrict__ intervals,
           const float* __restrict__ w0, const float* __restrict__ b0,
           const float* __restrict__ w1, const float* __restrict__ b1,
           const float* __restrict__ w2, const float* __restrict__ b2,
           const float* __restrict__ w3, const float* __restrict__ b3,
           const float* __restrict__ l1w, const float* __restrict__ l1b,
           const float* __restrict__ l2w, const float* __restrict__ l2b,
           float* out, unsigned char* ws) {
  const int tid = threadIdx.x;
  const int g = blockIdx.x;
  // XCD-packed mapping (xcd = bid&7 round-robin): row-group Rg occupies XCD pair
  // {2Rg, 2Rg+1} so its 270 KB logsig slice is L2-resident. Bijective.
  const int Rg = (g >> 1) & 3;                 // owned row-group
  const int h  = ((g >> 3) << 1) | (g & 1);    // owned head
  const int R = Rg * 128;
  const int r0 = R + 2 * h;                    // first owned batch row
  unsigned* BAR = (unsigned*)(ws + WS_BAR);
  unsigned rseq = 0;

  __shared__ __attribute__((aligned(16))) unsigned short w3lds[67584]; // 135.2 KB
  __shared__ float b3lds[528];
  __shared__ float intv[64];
  __shared__ float yst[2][64];
  __shared__ float hb1[2][128];
  __shared__ float hb2[2][128];
  __shared__ __attribute__((aligned(8))) unsigned short hdnS[2][128];
  __shared__ int sidx;

  if (tid < 64) intv[tid] = intervals[tid];
  for (int e = tid; e < 528; e += NTHR) b3lds[e] = b3[(size_t)h * 528 + e];

  // w3 head-slice -> LDS bf16 B-fragments (once)
  for (int e = tid; e < 8448; e += NTHR) {   // 33 nt * 4 kb * 64 lanes
    const int ln = e & 63, kb = (e >> 6) & 3, nt = e >> 8;
    const float* src = w3 + ((size_t)(h * 528 + nt * 16 + (ln & 15))) * 128 + kb * 32 + (ln >> 4) * 8;
    union { unsigned short s[8]; short8 v; } p;
    #pragma unroll
    for (int j = 0; j < 8; ++j) p.s[j] = f2bf(src[j]);
    *(short8*)(w3lds + e * 8) = p.v;
  }

  // Per-thread MLP weight residency: w1,w2 rows (half-K split) in VGPRs, f32 exact.
  const int mj = ((tid >> 6) & 3) * 32 + (tid & 31), mhalf = (tid >> 5) & 1;
  float4_ wr1[16], wr2[16];
  {
    const float4_* s1 = (const float4_*)(w1 + (size_t)mj * 128 + mhalf * 64);
    const float4_* s2 = (const float4_*)(w2 + (size_t)mj * 128 + mhalf * 64);
    #pragma unroll
    for (int i = 0; i < 16; ++i) { wr1[i] = s1[i]; wr2[i] = s2[i]; }
  }
  const float b0r = b0[mj], b1r = b1[mj], b2r = b2[mj];

  // y0 = x0 @ l1w.T + l1b for own 2 rows (tid<128: row=tid>>6, hh=tid&63)
  float y = 0.0f, kh[6];
  #pragma unroll
  for (int i = 0; i < 6; ++i) kh[i] = 0.0f;
  if (tid < 128) {
    const int row = tid >> 6, hh = tid & 63;
    float acc = l1b[hh];
    const float4_* xr = (const float4_*)(x0 + (size_t)(r0 + row) * 32);
    const float4_* wr = (const float4_*)(l1w + (size_t)hh * 32);
    #pragma unroll
    for (int d = 0; d < 8; ++d) {
      float4_ xv = xr[d], wvv = wr[d];
      acc = fmaf(xv[0], wvv[0], acc); acc = fmaf(xv[1], wvv[1], acc);
      acc = fmaf(xv[2], wvv[2], acc); acc = fmaf(xv[3], wvv[3], acc);
    }
    y = acc;
  }
  const float t0v = ts[0];
  const float dtv = (ts[128] - t0v) * (1.0f / 256.0f);
  __syncthreads();

  // ---- 256 steps x 6 stages ----
  for (int stepi = 0; stepi < 256; ++stepi) {
    const int sg = stepi * 6;
    rk_stage<0>(stepi, sg + 0, h, Rg, R, r0, kh, y, t0v, dtv, wr1, wr2, b0r, b1r, b2r,
                ws, BAR, rseq, logsig, w0, w3lds, b3lds, intv, yst, hb1, hb2, hdnS, &sidx);
    rk_stage<1>(stepi, sg + 1, h, Rg, R, r0, kh, y, t0v, dtv, wr1, wr2, b0r, b1r, b2r,
                ws, BAR, rseq, logsig, w0, w3lds, b3lds, intv, yst, hb1, hb2, hdnS, &sidx);
    rk_stage<2>(stepi, sg + 2, h, Rg, R, r0, kh, y, t0v, dtv, wr1, wr2, b0r, b1r, b2r,
                ws, BAR, rseq, logsig, w0, w3lds, b3lds, intv, yst, hb1, hb2, hdnS, &sidx);
    rk_stage<3>(stepi, sg + 3, h, Rg, R, r0, kh, y, t0v, dtv, wr1, wr2, b0r, b1r, b2r,
                ws, BAR, rseq, logsig, w0, w3lds, b3lds, intv, yst, hb1, hb2, hdnS, &sidx);
    rk_stage<4>(stepi, sg + 4, h, Rg, R, r0, kh, y, t0v, dtv, wr1, wr2, b0r, b1r, b2r,
                ws, BAR, rseq, logsig, w0, w3lds, b3lds, intv, yst, hb1, hb2, hdnS, &sidx);
    rk_stage<5>(stepi, sg + 5, h, Rg, R, r0, kh, y, t0v, dtv, wr1, wr2, b0r, b1r, b2r,
                ws, BAR, rseq, logsig, w0, w3lds, b3lds, intv, yst, hb1, hb2, hdnS, &sidx);
  }

  // ---- epilogue: ingest k6 of step 255, final y, head, softmax (own 2 rows) ----
  {
    float* KF = (float*)(ws + WS_KF);
    if (tid < 128) {
      const int row = tid >> 6, hh = tid & 63;
      kh[5] = LOADC(&KF[(size_t)32768 + (size_t)(r0 + row) * 64 + hh]);  // sg=1535 parity 1
      y += dtv * (0.09646076681806523f * kh[0] + 0.01f * kh[1]
                + 0.4798896504144996f * kh[2] + 1.379008574103742f * kh[3]
                - 3.290069515436081f * kh[4] + 2.324710524099774f * kh[5]);
      yst[row][hh] = y;
    }
    __syncthreads();
    if (tid < 20) {
      const int row = tid / 10, c = tid % 10;
      float acc = l2b[c];
      const float* wr = l2w + c * 64;
      #pragma unroll
      for (int i2 = 0; i2 < 64; ++i2) acc = fmaf(yst[row][i2], wr[i2], acc);
      hb1[row][c] = acc;
    }
    __syncthreads();
    if (tid < 2) {
      const int row = tid;
      float mx = -1e30f;
      for (int c = 0; c < 10; ++c) mx = fmaxf(mx, hb1[row][c]);
      float ev[10], den = 0.0f;
      for (int c = 0; c < 10; ++c) { ev[c] = expf(hb1[row][c] - mx); den += ev[c]; }
      const float rd = 1.0f / den;
      for (int c = 0; c < 10; ++c) out[(size_t)(r0 + row) * 10 + c] = ev[c] * rd;
    }
  }
}

extern "C" void kernel_launch(void* const* d_in, const int* in_sizes, int n_in,
                              void* d_out, int out_size, void* d_ws, size_t ws_size,
                              hipStream_t stream) {
  (void)in_sizes; (void)n_in; (void)out_size; (void)ws_size;
  const float* ts        = (const float*)d_in[0];
  const float* logsig    = (const float*)d_in[1];
  const float* x0        = (const float*)d_in[2];
  const float* intervals = (const float*)d_in[3];
  const float* w0        = (const float*)d_in[4];
  const float* b0        = (const float*)d_in[5];
  const float* w1        = (const float*)d_in[6];
  const float* b1        = (const float*)d_in[7];
  const float* w2        = (const float*)d_in[8];
  const float* b2        = (const float*)d_in[9];
  const float* w3        = (const float*)d_in[10];
  const float* b3        = (const float*)d_in[11];
  const float* l1w       = (const float*)d_in[12];
  const float* l1b       = (const float*)d_in[13];
  const float* l2w       = (const float*)d_in[14];
  const float* l2b       = (const float*)d_in[15];
  float* out = (float*)d_out;
  unsigned char* ws = (unsigned char*)d_ws;

  hipMemsetAsync(d_ws, 0, 12288, stream);  // zero all barrier counters

  void* args[] = { &ts, &logsig, &x0, &intervals, &w0, &b0, &w1, &b1,
                   &w2, &b2, &w3, &b3, &l1w, &l1b, &l2w, &l2b, &out, &ws };
  hipLaunchCooperativeKernel((void*)rde_kernel, dim3(NBLK), dim3(NTHR), args, 0, stream);
}

// Round 5
// 35447.375 us; speedup vs baseline: 1.2125x; 1.2125x over previous
//
#include <hip/hip_runtime.h>
#include <stdint.h>

#define NBLK 256
#define NTHR 512

typedef __attribute__((ext_vector_type(8))) short short8;
typedef __attribute__((ext_vector_type(4))) float float4_;

// ---- workspace ----
// BAR: per-Rg sets at lines 32+Rg*16+(0..9) (leaf 0..7, root 8, gen 9). memset first 12288 B.
#define WS_BAR  0
#define WS_HDNF 16384                     // hdn fragments: 4Rg * 32 * 512 shorts = 131072 B
#define WS_KF   (16384 + 131072)          // 2 x 512*64 f32 (double-buffered k) = 262144 B

#define LOADC(p)    __hip_atomic_load((p),  __ATOMIC_RELAXED, __HIP_MEMORY_SCOPE_SYSTEM)
#define STOREC(p,v) __hip_atomic_store((p), (v), __ATOMIC_RELAXED, __HIP_MEMORY_SCOPE_SYSTEM)

__device__ __forceinline__ unsigned short f2bf(float x) {
  union { float f; unsigned u; } v; v.f = x;
  return (unsigned short)((v.u + 0x7fffu + ((v.u >> 16) & 1u)) >> 16);
}
__device__ __forceinline__ float fast_exp(float x) {
  return __builtin_amdgcn_exp2f(x * 1.4426950408889634f);
}
__device__ __forceinline__ float fast_tanh(float x) {
  float e = __builtin_amdgcn_exp2f(x * 2.8853900817779268f);
  return fmaf(-2.0f, __builtin_amdgcn_rcpf(e + 1.0f), 1.0f);
}
__device__ __forceinline__ float fast_silu(float x) {
  float e = fast_exp(-x);
  return x * __builtin_amdgcn_rcpf(1.0f + e);
}

// Row-group-local barrier over 64 blocks: 8 leaves x 8 (leaf = h&7) + root + gen.
// Proven design: one arriving lane per block, fetch_add tree, gen poll + s_sleep.
__device__ __forceinline__ void rgbar(unsigned* bar, int h, int Rg, unsigned bn) {
  __syncthreads();
  if (threadIdx.x == 0) {
    unsigned* base = bar + 32 * (32 + Rg * 16);
    unsigned* leaf = base + 32 * (h & 7);
    unsigned* root = base + 32 * 8;
    unsigned* gen  = base + 32 * 9;
    unsigned a = __hip_atomic_fetch_add(leaf, 1u, __ATOMIC_RELAXED, __HIP_MEMORY_SCOPE_SYSTEM);
    if (a == 8u * bn - 1u) {
      unsigned r = __hip_atomic_fetch_add(root, 1u, __ATOMIC_RELAXED, __HIP_MEMORY_SCOPE_SYSTEM);
      if (r == 8u * bn - 1u) STOREC(gen, bn);
    }
    while (LOADC(gen) < bn) __builtin_amdgcn_s_sleep(1);
  }
  __syncthreads();
}

template<int SIN>
__device__ __forceinline__ void rk_stage(
    int stepi, int sg, int h, int Rg, int R, int r0,
    float (&kh)[6], float& y, float t0v, float dtv,
    const float4_ (&wq1)[8], const float4_ (&wq2)[8],
    float b0r, float b1q, float b2q,
    unsigned char* ws, unsigned* BAR, unsigned& rseq,
    const float* logsig, const float* w0,
    unsigned short* w3lds, float* b3lds, float* intv,
    float (*yst)[64], float (*hb1)[128], float (*hb2)[128],
    unsigned short (*hdnS)[128], int* sidxp) {
  const int tid = threadIdx.x;
  const int lane = tid & 63, wv = tid >> 6;
  const int col = lane & 15, qd = lane >> 4;
  // layer-1 mapping: tid = (row<<8) | (jhi<<6) | (half<<5) | jlo ; j = jhi*32+jlo
  const int mrow = tid >> 8, mj = ((tid >> 6) & 3) * 32 + (tid & 31), mhalf = (tid >> 5) & 1;
  // layers-2/3 mapping (quarter-K, both rows per thread): j = wv*16 + (lane&15)
  const int qj = wv * 16 + col, qq = qd;
  unsigned* HDNF = (unsigned*)(ws + WS_HDNF);
  float* KF  = (float*)(ws + WS_KF);

  // ---- phase 1: ingest k (2 rows), RK combine, MLP ----
  if (sg > 0 && tid < 128) {
    const float* KFr = KF + ((sg & 1) ^ 1) * 32768;
    constexpr int pi = (SIN == 0) ? 5 : SIN - 1;
    kh[pi] = LOADC(&KFr[(size_t)(r0 + (tid >> 6)) * 64 + (tid & 63)]);
  }
  if (tid < 128) {
    float ystv;
    if constexpr (SIN == 0) {
      if (sg > 0) {
        y += dtv * (0.09646076681806523f * kh[0] + 0.01f * kh[1]
                  + 0.4798896504144996f * kh[2] + 1.379008574103742f * kh[3]
                  - 3.290069515436081f * kh[4] + 2.324710524099774f * kh[5]);
      }
      ystv = y;
    } else if constexpr (SIN == 1) {
      ystv = y + dtv * (0.161f * kh[0]);
    } else if constexpr (SIN == 2) {
      ystv = y + dtv * (-0.008480655492356989f * kh[0] + 0.335480655492357f * kh[1]);
    } else if constexpr (SIN == 3) {
      ystv = y + dtv * (2.8971530571054935f * kh[0] - 6.359448489975075f * kh[1]
                      + 4.3622954328695815f * kh[2]);
    } else if constexpr (SIN == 4) {
      ystv = y + dtv * (5.325864828439257f * kh[0] - 11.748883564062828f * kh[1]
                      + 7.4955393428898365f * kh[2] - 0.09249506636175525f * kh[3]);
    } else {
      ystv = y + dtv * (5.86145544294642f * kh[0] - 12.92096931784711f * kh[1]
                      + 8.159367898576159f * kh[2] - 0.071584973281401f * kh[3]
                      - 0.028269050394068383f * kh[4]);
    }
    yst[tid >> 6][tid & 63] = ystv;
  }
  // searchsorted for current stage time (exact f32 compare vs intervals input)
  {
    float tb = __fadd_rn(t0v, __fmul_rn((float)stepi, dtv));
    float t_cur;
    if constexpr (SIN == 0) t_cur = tb;
    else {
      constexpr float cS = (SIN == 1) ? 0.161f : (SIN == 2) ? 0.327f : (SIN == 3) ? 0.9f
                         : (SIN == 4) ? 0.9800255409045097f : 1.0f;
      t_cur = __fadd_rn(tb, __fmul_rn(cS, dtv));
    }
    if (tid < 64) {
      unsigned long long m1 = __ballot(intv[tid] < t_cur);
      if (tid == 0) *sidxp = (int)__popcll(m1);
    }
  }
  __syncthreads();
  const int idx = *sidxp;

  // MLP layer 1 (w0 streamed, K=64 half-split): all 512 threads
  {
    const float4_* wrp = (const float4_*)(w0 + (size_t)mj * 64 + mhalf * 32);
    const float* yp = &yst[mrow][mhalf * 32];
    float ac0 = 0.0f, ac1 = 0.0f;
    #pragma unroll
    for (int i4 = 0; i4 < 8; ++i4) {
      float4_ wvv = wrp[i4];
      float s = fmaf(yp[4*i4+0], wvv[0], yp[4*i4+1] * wvv[1]);
      s = fmaf(yp[4*i4+2], wvv[2], s);
      s = fmaf(yp[4*i4+3], wvv[3], s);
      if (i4 & 1) ac1 += s; else ac0 += s;
    }
    float v = ac0 + ac1;
    v += __shfl_xor(v, 32);
    if (mhalf == 0) hb1[mrow][mj] = fast_silu(v + b0r);
  }
  __syncthreads();
  // MLP layer 2 (w1 quarter-rows in VGPRs, both batch rows interleaved)
  {
    const float* h0 = &hb1[0][qq * 32];
    const float* h1 = &hb1[1][qq * 32];
    float a0 = 0.0f, a1 = 0.0f, c0 = 0.0f, c1 = 0.0f;
    #pragma unroll
    for (int i4 = 0; i4 < 8; ++i4) {
      float4_ wvv = wq1[i4];
      float s0 = fmaf(h0[4*i4+0], wvv[0], h0[4*i4+1] * wvv[1]);
      s0 = fmaf(h0[4*i4+2], wvv[2], s0);
      s0 = fmaf(h0[4*i4+3], wvv[3], s0);
      float s1 = fmaf(h1[4*i4+0], wvv[0], h1[4*i4+1] * wvv[1]);
      s1 = fmaf(h1[4*i4+2], wvv[2], s1);
      s1 = fmaf(h1[4*i4+3], wvv[3], s1);
      if (i4 & 1) { c0 += s0; c1 += s1; } else { a0 += s0; a1 += s1; }
    }
    float v0 = a0 + c0, v1 = a1 + c1;
    v0 += __shfl_xor(v0, 16); v0 += __shfl_xor(v0, 32);
    v1 += __shfl_xor(v1, 16); v1 += __shfl_xor(v1, 32);
    if (qq == 0) {
      hb2[0][qj] = fast_silu(v0 + b1q);
      hb2[1][qj] = fast_silu(v1 + b1q);
    }
  }
  __syncthreads();
  // MLP layer 3 (w2 quarter-rows in VGPRs) -> bf16 hdn
  {
    const float* h0 = &hb2[0][qq * 32];
    const float* h1 = &hb2[1][qq * 32];
    float a0 = 0.0f, a1 = 0.0f, c0 = 0.0f, c1 = 0.0f;
    #pragma unroll
    for (int i4 = 0; i4 < 8; ++i4) {
      float4_ wvv = wq2[i4];
      float s0 = fmaf(h0[4*i4+0], wvv[0], h0[4*i4+1] * wvv[1]);
      s0 = fmaf(h0[4*i4+2], wvv[2], s0);
      s0 = fmaf(h0[4*i4+3], wvv[3], s0);
      float s1 = fmaf(h1[4*i4+0], wvv[0], h1[4*i4+1] * wvv[1]);
      s1 = fmaf(h1[4*i4+2], wvv[2], s1);
      s1 = fmaf(h1[4*i4+3], wvv[3], s1);
      if (i4 & 1) { c0 += s0; c1 += s1; } else { a0 += s0; a1 += s1; }
    }
    float v0 = a0 + c0, v1 = a1 + c1;
    v0 += __shfl_xor(v0, 16); v0 += __shfl_xor(v0, 32);
    v1 += __shfl_xor(v1, 16); v1 += __shfl_xor(v1, 32);
    if (qq == 0) {
      hdnS[0][qj] = f2bf(fast_silu(v0 + b2q));
      hdnS[1][qj] = f2bf(fast_silu(v1 + b2q));
    }
  }
  __syncthreads();
  // pack-store hdn into A-fragment layout in WS (dword stores)
  if (tid < 128) {
    const int row = tid >> 6, u = tid & 63;
    const int lb = 2 * h + row;            // local row within Rg
    const int tile = lb >> 4, colp = lb & 15;
    const int j0 = 2 * u;
    const int kb = j0 >> 5, qdp = (j0 >> 3) & 3, jj = j0 & 7;
    unsigned v = (unsigned)hdnS[row][j0] | ((unsigned)hdnS[row][j0 + 1] << 16);
    unsigned i16 = (unsigned)((Rg * 32 + tile * 4 + kb) * 512 + qdp * 128 + colp * 8 + jj);
    STOREC(&HDNF[i16 >> 1], v);
  }
  // ---- barrier 1: hdn exchange within row-group ----
  ++rseq; rgbar(BAR, h, Rg, rseq);

  // ---- phase 2: GEMM 128 x 528 x 128 (wave wv owns m-tile wv), no internal syncs ----
  {
    const unsigned long long* H64 = (const unsigned long long*)HDNF;
    union { unsigned long long u[2]; short8 s; } af[4];
    #pragma unroll
    for (int kb = 0; kb < 4; ++kb) {
      const unsigned i16 = (unsigned)((Rg * 32 + wv * 4 + kb) * 512 + lane * 8);
      af[kb].u[0] = LOADC(&H64[i16 >> 2]);
      af[kb].u[1] = LOADC(&H64[(i16 >> 2) + 1]);
    }
    // direct reads of read-only logsig[b][idx][1+l] (L2-resident per XCD pair)
    const float* sp0 = logsig + (size_t)(R + wv * 16 + qd * 4) * 34385 + (size_t)idx * 529 + 1;
    const float* sp1 = sp0 + 34385;
    const float* sp2 = sp0 + 2 * 34385;
    const float* sp3 = sp0 + 3 * 34385;
    float kp[4] = {0.0f, 0.0f, 0.0f, 0.0f};
    #pragma unroll 2
    for (int nt = 0; nt < 33; ++nt) {
      const int l = nt * 16 + col;
      const float bv = b3lds[l];
      float4_ acc; acc[0] = bv; acc[1] = bv; acc[2] = bv; acc[3] = bv;
      #pragma unroll
      for (int kb = 0; kb < 4; ++kb) {
        const short8 bf = *(const short8*)(w3lds + ((nt * 4 + kb) * 64 + lane) * 8);
        acc = __builtin_amdgcn_mfma_f32_16x16x32_bf16(af[kb].s, bf, acc, 0, 0, 0);
      }
      kp[0] = fmaf(fast_tanh(acc[0]), sp0[l], kp[0]);
      kp[1] = fmaf(fast_tanh(acc[1]), sp1[l], kp[1]);
      kp[2] = fmaf(fast_tanh(acc[2]), sp2[l], kp[2]);
      kp[3] = fmaf(fast_tanh(acc[3]), sp3[l], kp[3]);
    }
    #pragma unroll
    for (int r = 0; r < 4; ++r) {
      float v = kp[r];
      v += __shfl_xor(v, 1); v += __shfl_xor(v, 2);
      v += __shfl_xor(v, 4); v += __shfl_xor(v, 8);
      kp[r] = v;
    }
    if (col == 0) {
      float* KFw = KF + (sg & 1) * 32768;
      #pragma unroll
      for (int r = 0; r < 4; ++r)
        STOREC(&KFw[(size_t)(R + wv * 16 + qd * 4 + r) * 64 + h], kp[r]);
    }
  }
  // ---- barrier 2: k exchange within row-group ----
  ++rseq; rgbar(BAR, h, Rg, rseq);
}

// __launch_bounds__(512,1): VGPR cap 512, but static demand is ~200 (64 weight
// VGPRs + working set) so the allocator lands < 256 and the 8-wave workgroup
// stays launchable (2 waves/SIMD x <=256 VGPR). LDS caps us at 1 block/CU anyway.
__global__ void __launch_bounds__(NTHR, 1)
rde_kernel(const float* __restrict__ ts, const float* __restrict__ logsig,
           const float* __restrict__ x0, const float* __restrict__ intervals,
           const float* __restrict__ w0, const float* __restrict__ b0,
           const float* __restrict__ w1, const float* __restrict__ b1,
           const float* __restrict__ w2, const float* __restrict__ b2,
           const float* __restrict__ w3, const float* __restrict__ b3,
           const float* __restrict__ l1w, const float* __restrict__ l1b,
           const float* __restrict__ l2w, const float* __restrict__ l2b,
           float* out, unsigned char* ws) {
  const int tid = threadIdx.x;
  const int g = blockIdx.x;
  // XCD-packed mapping (xcd = bid&7 round-robin): row-group Rg occupies XCD pair
  // {2Rg, 2Rg+1} so its 270 KB logsig slice is L2-resident. Bijective.
  const int Rg = (g >> 1) & 3;                 // owned row-group
  const int h  = ((g >> 3) << 1) | (g & 1);    // owned head
  const int R = Rg * 128;
  const int r0 = R + 2 * h;                    // first owned batch row
  unsigned* BAR = (unsigned*)(ws + WS_BAR);
  unsigned rseq = 0;

  __shared__ __attribute__((aligned(16))) unsigned short w3lds[67584]; // 135.2 KB
  __shared__ float b3lds[528];
  __shared__ float intv[64];
  __shared__ float yst[2][64];
  __shared__ float hb1[2][128];
  __shared__ float hb2[2][128];
  __shared__ __attribute__((aligned(8))) unsigned short hdnS[2][128];
  __shared__ int sidx;

  if (tid < 64) intv[tid] = intervals[tid];
  for (int e = tid; e < 528; e += NTHR) b3lds[e] = b3[(size_t)h * 528 + e];

  // w3 head-slice -> LDS bf16 B-fragments (once)
  for (int e = tid; e < 8448; e += NTHR) {   // 33 nt * 4 kb * 64 lanes
    const int ln = e & 63, kb = (e >> 6) & 3, nt = e >> 8;
    const float* src = w3 + ((size_t)(h * 528 + nt * 16 + (ln & 15))) * 128 + kb * 32 + (ln >> 4) * 8;
    union { unsigned short s[8]; short8 v; } p;
    #pragma unroll
    for (int j = 0; j < 8; ++j) p.s[j] = f2bf(src[j]);
    *(short8*)(w3lds + e * 8) = p.v;
  }

  // Per-thread MLP weight residency (quarter-K split): each thread holds a
  // 32-float quarter-row of w1 and w2 (8 float4 each = 64 VGPRs total), f32 exact.
  const int mj = ((tid >> 6) & 3) * 32 + (tid & 31);         // layer-1 j
  const int qj = (tid >> 6) * 16 + (tid & 15), qq = (tid >> 4) & 3;  // layer-2/3 j, quarter
  float4_ wq1[8], wq2[8];
  {
    const float4_* s1 = (const float4_*)(w1 + (size_t)qj * 128 + qq * 32);
    const float4_* s2 = (const float4_*)(w2 + (size_t)qj * 128 + qq * 32);
    #pragma unroll
    for (int i = 0; i < 8; ++i) { wq1[i] = s1[i]; wq2[i] = s2[i]; }
  }
  const float b0r = b0[mj], b1q = b1[qj], b2q = b2[qj];

  // y0 = x0 @ l1w.T + l1b for own 2 rows (tid<128: row=tid>>6, hh=tid&63)
  float y = 0.0f, kh[6];
  #pragma unroll
  for (int i = 0; i < 6; ++i) kh[i] = 0.0f;
  if (tid < 128) {
    const int row = tid >> 6, hh = tid & 63;
    float acc = l1b[hh];
    const float4_* xr = (const float4_*)(x0 + (size_t)(r0 + row) * 32);
    const float4_* wr = (const float4_*)(l1w + (size_t)hh * 32);
    #pragma unroll
    for (int d = 0; d < 8; ++d) {
      float4_ xv = xr[d], wvv = wr[d];
      acc = fmaf(xv[0], wvv[0], acc); acc = fmaf(xv[1], wvv[1], acc);
      acc = fmaf(xv[2], wvv[2], acc); acc = fmaf(xv[3], wvv[3], acc);
    }
    y = acc;
  }
  const float t0v = ts[0];
  const float dtv = (ts[128] - t0v) * (1.0f / 256.0f);
  __syncthreads();

  // ---- 256 steps x 6 stages ----
  for (int stepi = 0; stepi < 256; ++stepi) {
    const int sg = stepi * 6;
    rk_stage<0>(stepi, sg + 0, h, Rg, R, r0, kh, y, t0v, dtv, wq1, wq2, b0r, b1q, b2q,
                ws, BAR, rseq, logsig, w0, w3lds, b3lds, intv, yst, hb1, hb2, hdnS, &sidx);
    rk_stage<1>(stepi, sg + 1, h, Rg, R, r0, kh, y, t0v, dtv, wq1, wq2, b0r, b1q, b2q,
                ws, BAR, rseq, logsig, w0, w3lds, b3lds, intv, yst, hb1, hb2, hdnS, &sidx);
    rk_stage<2>(stepi, sg + 2, h, Rg, R, r0, kh, y, t0v, dtv, wq1, wq2, b0r, b1q, b2q,
                ws, BAR, rseq, logsig, w0, w3lds, b3lds, intv, yst, hb1, hb2, hdnS, &sidx);
    rk_stage<3>(stepi, sg + 3, h, Rg, R, r0, kh, y, t0v, dtv, wq1, wq2, b0r, b1q, b2q,
                ws, BAR, rseq, logsig, w0, w3lds, b3lds, intv, yst, hb1, hb2, hdnS, &sidx);
    rk_stage<4>(stepi, sg + 4, h, Rg, R, r0, kh, y, t0v, dtv, wq1, wq2, b0r, b1q, b2q,
                ws, BAR, rseq, logsig, w0, w3lds, b3lds, intv, yst, hb1, hb2, hdnS, &sidx);
    rk_stage<5>(stepi, sg + 5, h, Rg, R, r0, kh, y, t0v, dtv, wq1, wq2, b0r, b1q, b2q,
                ws, BAR, rseq, logsig, w0, w3lds, b3lds, intv, yst, hb1, hb2, hdnS, &sidx);
  }

  // ---- epilogue: ingest k6 of step 255, final y, head, softmax (own 2 rows) ----
  {
    float* KF = (float*)(ws + WS_KF);
    if (tid < 128) {
      const int row = tid >> 6, hh = tid & 63;
      kh[5] = LOADC(&KF[(size_t)32768 + (size_t)(r0 + row) * 64 + hh]);  // sg=1535 parity 1
      y += dtv * (0.09646076681806523f * kh[0] + 0.01f * kh[1]
                + 0.4798896504144996f * kh[2] + 1.379008574103742f * kh[3]
                - 3.290069515436081f * kh[4] + 2.324710524099774f * kh[5]);
      yst[row][hh] = y;
    }
    __syncthreads();
    if (tid < 20) {
      const int row = tid / 10, c = tid % 10;
      float acc = l2b[c];
      const float* wr = l2w + c * 64;
      #pragma unroll
      for (int i2 = 0; i2 < 64; ++i2) acc = fmaf(yst[row][i2], wr[i2], acc);
      hb1[row][c] = acc;
    }
    __syncthreads();
    if (tid < 2) {
      const int row = tid;
      float mx = -1e30f;
      for (int c = 0; c < 10; ++c) mx = fmaxf(mx, hb1[row][c]);
      float ev[10], den = 0.0f;
      for (int c = 0; c < 10; ++c) { ev[c] = expf(hb1[row][c] - mx); den += ev[c]; }
      const float rd = 1.0f / den;
      for (int c = 0; c < 10; ++c) out[(size_t)(r0 + row) * 10 + c] = ev[c] * rd;
    }
  }
}

extern "C" void kernel_launch(void* const* d_in, const int* in_sizes, int n_in,
                              void* d_out, int out_size, void* d_ws, size_t ws_size,
                              hipStream_t stream) {
  (void)in_sizes; (void)n_in; (void)out_size; (void)ws_size;
  const float* ts        = (const float*)d_in[0];
  const float* logsig    = (const float*)d_in[1];
  const float* x0        = (const float*)d_in[2];
  const float* intervals = (const float*)d_in[3];
  const float* w0        = (const float*)d_in[4];
  const float* b0        = (const float*)d_in[5];
  const float* w1        = (const float*)d_in[6];
  const float* b1        = (const float*)d_in[7];
  const float* w2        = (const float*)d_in[8];
  const float* b2        = (const float*)d_in[9];
  const float* w3        = (const float*)d_in[10];
  const float* b3        = (const float*)d_in[11];
  const float* l1w       = (const float*)d_in[12];
  const float* l1b       = (const float*)d_in[13];
  const float* l2w       = (const float*)d_in[14];
  const float* l2b       = (const float*)d_in[15];
  float* out = (float*)d_out;
  unsigned char* ws = (unsigned char*)d_ws;

  hipMemsetAsync(d_ws, 0, 12288, stream);  // zero all barrier counters

  void* args[] = { &ts, &logsig, &x0, &intervals, &w0, &b0, &w1, &b1,
                   &w2, &b2, &w3, &b3, &l1w, &l1b, &l2w, &l2b, &out, &ws };
  hipLaunchCooperativeKernel((void*)rde_kernel, dim3(NBLK), dim3(NTHR), args, 0, stream);
}